// Round 1
// 1121.730 us; speedup vs baseline: 1.2233x; 1.2233x over previous
//
#include <hip/hip_runtime.h>
#include <stdint.h>

// EfficientFusionLayer on MI355X (gfx950).  B=16384, DIM=1024, HID=2048.
// fp32 in/out; internals bf16 MFMA (16x16x32).
// seq-len-1 MHA folded: attn(x) = x@(Wo@Wv)^T + (Wo@bv + bo)  -- one GEMM.
// GEMM: 256x256 tile, BK=64, 8 waves, 8-phase interleave with counted vmcnt
// (T1 XCD swizzle + T3/T4 counted-vmcnt pipeline + T5 setprio; m194-m201
// template re-derived).  LDS 128 KiB double-buffered, XOR col-group swizzle
// (same family as the previous 128^2 kernel, measured 0 bank conflicts).

typedef unsigned short u16;
typedef __bf16 bf16x8 __attribute__((ext_vector_type(8)));
typedef float f32x4 __attribute__((ext_vector_type(4)));

__device__ __forceinline__ u16 f2bf(float f) {
    uint32_t x = __float_as_uint(f);
    uint32_t r = (x + 0x7fffu + ((x >> 16) & 1u)) >> 16;   // round-nearest-even
    return (u16)r;
}
__device__ __forceinline__ float bf2f(u16 u) {
    return __uint_as_float(((uint32_t)u) << 16);
}

// async global->LDS, 16B per lane; deposit = wave-uniform base + lane*16
__device__ __forceinline__ void glds16(const u16* g, u16* l) {
    __builtin_amdgcn_global_load_lds(
        (__attribute__((address_space(1))) void*)g,
        (__attribute__((address_space(3))) void*)l, 16, 0, 0);
}

// ---------------------------------------------------------------------------
// fp32 -> bf16 convert (4 elems/thread, n % 1024 == 0)
__global__ __launch_bounds__(256) void cvtk(const float* __restrict__ src,
                                            u16* __restrict__ dst) {
    size_t i = ((size_t)blockIdx.x * 256 + threadIdx.x) * 4;
    float4 v = *(const float4*)&src[i];
    ushort4 o;
    o.x = f2bf(v.x); o.y = f2bf(v.y); o.z = f2bf(v.z); o.w = f2bf(v.w);
    *(ushort4*)&dst[i] = o;
}

// transposing fp32 -> bf16 convert for the 4 Wv matrices (1024x1024 each)
struct Ptr4 { const float* p[4]; };
__global__ __launch_bounds__(256) void tcvtk(Ptr4 src, u16* __restrict__ dst) {
    __shared__ float t[32][33];
    const int z = blockIdx.z;
    const float* s = src.p[z];
    const int bx = blockIdx.x * 32, by = blockIdx.y * 32;
    const int tx = threadIdx.x & 31, ty = threadIdx.x >> 5;   // 32 x 8
#pragma unroll
    for (int i = 0; i < 32; i += 8)
        t[ty + i][tx] = s[(size_t)(by + ty + i) * 1024 + bx + tx];
    __syncthreads();
    u16* d = dst + (size_t)z * (1024 * 1024);
#pragma unroll
    for (int i = 0; i < 32; i += 8)
        d[(size_t)(bx + ty + i) * 1024 + by + tx] = f2bf(t[tx][ty + i]);
}

// fused bias: bc_z[r] = dot(Wo_z[r,:], bv_z) + bo_z[r]  (fp32, exact inputs)
struct BiasArgs { const float* Wo[4]; const float* bv[4]; const float* bo[4]; };
__global__ __launch_bounds__(256) void biask(BiasArgs a, float* __restrict__ out) {
    const int z = blockIdx.y;
    const int row = blockIdx.x * 4 + (threadIdx.x >> 6);
    const int lane = threadIdx.x & 63;
    const float* w = a.Wo[z] + (size_t)row * 1024 + lane * 16;
    const float* v = a.bv[z] + lane * 16;
    float s = 0.f;
#pragma unroll
    for (int i = 0; i < 16; i += 4) {
        float4 w4 = *(const float4*)&w[i];
        float4 v4 = *(const float4*)&v[i];
        s += w4.x * v4.x + w4.y * v4.y + w4.z * v4.z + w4.w * v4.w;
    }
#pragma unroll
    for (int o = 1; o < 64; o <<= 1) s += __shfl_xor(s, o);
    if (lane == 0) out[(size_t)z * 1024 + row] = s + a.bo[z][row];
}

// new_context = 0.5*(v_out + t_out)
__global__ __launch_bounds__(256) void ctxk(const float* __restrict__ a,
                                            const float* __restrict__ b,
                                            float* __restrict__ o) {
    size_t i = ((size_t)blockIdx.x * 256 + threadIdx.x) * 4;
    float4 va = *(const float4*)&a[i];
    float4 vb = *(const float4*)&b[i];
    float4 vo;
    vo.x = 0.5f * (va.x + vb.x); vo.y = 0.5f * (va.y + vb.y);
    vo.z = 0.5f * (va.z + vb.z); vo.w = 0.5f * (va.w + vb.w);
    *(float4*)&o[i] = vo;
}

// ---------------------------------------------------------------------------
// LayerNorm over D=1024: out_bf16 = LN(x_f32 + s*(a1_bf16 [+ a2_bf16])) * g + be
__global__ __launch_bounds__(256) void ln_kernel(
    const float* __restrict__ x, const u16* __restrict__ a1,
    const u16* __restrict__ a2, float s,
    const float* __restrict__ g, const float* __restrict__ be,
    u16* __restrict__ out) {
    const int tid = threadIdx.x;
    const size_t base = (size_t)blockIdx.x * 1024;
    const int i0 = tid * 4;

    float4 xv = *(const float4*)&x[base + i0];
    ushort4 u1 = *(const ushort4*)&a1[base + i0];
    float add[4] = {bf2f(u1.x), bf2f(u1.y), bf2f(u1.z), bf2f(u1.w)};
    if (a2) {
        ushort4 u2 = *(const ushort4*)&a2[base + i0];
        add[0] += bf2f(u2.x); add[1] += bf2f(u2.y);
        add[2] += bf2f(u2.z); add[3] += bf2f(u2.w);
    }
    float v[4] = {xv.x, xv.y, xv.z, xv.w};
    float sum = 0.f, ss = 0.f;
#pragma unroll
    for (int j = 0; j < 4; ++j) {
        v[j] += s * add[j];
        sum += v[j];
        ss += v[j] * v[j];
    }
#pragma unroll
    for (int o = 1; o < 64; o <<= 1) {
        sum += __shfl_xor(sum, o);
        ss  += __shfl_xor(ss, o);
    }
    __shared__ float s1[4], s2[4];
    if ((tid & 63) == 0) { s1[tid >> 6] = sum; s2[tid >> 6] = ss; }
    __syncthreads();
    sum = s1[0] + s1[1] + s1[2] + s1[3];
    ss  = s2[0] + s2[1] + s2[2] + s2[3];
    const float mean = sum * (1.f / 1024.f);
    const float var  = ss * (1.f / 1024.f) - mean * mean;
    const float inv  = rsqrtf(var + 1e-5f);

    float4 gv = *(const float4*)&g[i0];
    float4 bv = *(const float4*)&be[i0];
    ushort4 o4;
    o4.x = f2bf((v[0] - mean) * inv * gv.x + bv.x);
    o4.y = f2bf((v[1] - mean) * inv * gv.y + bv.y);
    o4.z = f2bf((v[2] - mean) * inv * gv.z + bv.z);
    o4.w = f2bf((v[3] - mean) * inv * gv.w + bv.w);
    *(ushort4*)&out[base + i0] = o4;
}

// ---------------------------------------------------------------------------
// NT GEMM: C[M,N] = A[M,K] @ W[N,K]^T + bias, bf16 in, fp32 acc.
// 256x256 tile, BK=64, 512 thr (8 waves, 2Mx4N), per-wave C = 128x64.
// 8-phase pipeline (4 phases/K-tile, 2 K-tiles per LDS double-buffer):
//   phase p of tile t: ds_read A m-reps {2p,2p+1} (+ all B in p=0);
//   stage one half-tile (p=0,1: A(t+1); p=2,3: B(t+2)); bar; lgkmcnt(0);
//   setprio(1); 16 MFMA; setprio(0); [p=3: vmcnt(4)] bar.
// vmcnt(4) at tile boundary = the 4 B(t+2) loads stay in flight across the
// barrier; needed data (A(t+1)) was issued 2-3 phases earlier.
// LDS [buf][A/B][khalf][256 rows x 32 cols], col-group XOR swizzle
// grp_phys = grp ^ ((row>>1)&3): read b128 = 2-way bank alias = free.
// Staging deposits are linear 1KB/wave-call; the inverse swizzle is applied
// to the per-lane GLOBAL source address (m173 both-sides rule).
// mode 0: bf16 out = acc+bias   1: bf16 out = relu(acc+bias)
// mode 2: fp32 out = acc+bias+bf2f(resid).  blockIdx.z batches (strides elems).
#define GBAR()  asm volatile("s_barrier" ::: "memory")
#define LGKM0() asm volatile("s_waitcnt lgkmcnt(0)" ::: "memory")

#define PH_READ_A(mi0)                                                        \
    a0[0] = *(const bf16x8*)&LDS[b][0][0][arow + (mi0) * 512];                \
    a0[1] = *(const bf16x8*)&LDS[b][0][1][arow + (mi0) * 512];                \
    a1[0] = *(const bf16x8*)&LDS[b][0][0][arow + ((mi0) + 1) * 512];          \
    a1[1] = *(const bf16x8*)&LDS[b][0][1][arow + ((mi0) + 1) * 512];

#define PH_MFMA(mi0)                                                          \
    __builtin_amdgcn_s_setprio(1);                                            \
    _Pragma("unroll")                                                         \
    for (int ni = 0; ni < 4; ++ni) {                                          \
        acc[mi0][ni] = __builtin_amdgcn_mfma_f32_16x16x32_bf16(               \
            a0[0], bF[ni][0], acc[mi0][ni], 0, 0, 0);                         \
        acc[mi0][ni] = __builtin_amdgcn_mfma_f32_16x16x32_bf16(               \
            a0[1], bF[ni][1], acc[mi0][ni], 0, 0, 0);                         \
        acc[(mi0) + 1][ni] = __builtin_amdgcn_mfma_f32_16x16x32_bf16(         \
            a1[0], bF[ni][0], acc[(mi0) + 1][ni], 0, 0, 0);                   \
        acc[(mi0) + 1][ni] = __builtin_amdgcn_mfma_f32_16x16x32_bf16(         \
            a1[1], bF[ni][1], acc[(mi0) + 1][ni], 0, 0, 0);                   \
    }                                                                         \
    __builtin_amdgcn_s_setprio(0);

__global__ __launch_bounds__(512, 2) void gemm256(
    const u16* __restrict__ A, const u16* __restrict__ W,
    const float* __restrict__ bias,
    int M, int N, int K, int mode,
    const u16* __restrict__ resid,
    u16* __restrict__ out_bf, float* __restrict__ out_f,
    size_t sA, size_t sW, size_t sC) {
    __shared__ u16 LDS[2][2][2][8192];   // [buf][A/B][khalf][256*32] = 128 KiB

    const int tid  = threadIdx.x;
    const int lane = tid & 63;
    const int wv   = tid >> 6;               // 0..7
    const int wm   = wv >> 2, wn = wv & 3;   // 2 x 4 wave grid

    // T1: bijective XCD-chunked swizzle (m204)
    const int gx   = gridDim.x;
    const int nwg  = gx * gridDim.y;
    const int orig = blockIdx.y * gx + blockIdx.x;
    const int qq = nwg >> 3, rr = nwg & 7;
    const int xcd = orig & 7, loc = orig >> 3;
    const int wgid =
        (xcd < rr ? xcd * (qq + 1) : rr * (qq + 1) + (xcd - rr) * qq) + loc;
    const int M0 = (wgid / gx) * 256, N0 = (wgid % gx) * 256;

    const int z = blockIdx.z;
    A += (size_t)z * sA;
    W += (size_t)z * sW;

    const f32x4 fz = {0.f, 0.f, 0.f, 0.f};
    f32x4 acc[8][4];
#pragma unroll
    for (int i = 0; i < 8; ++i)
#pragma unroll
        for (int j = 0; j < 4; ++j) acc[i][j] = fz;

    // staging: wave wv covers tile rows [wv*32, wv*32+32); call c adds 16 rows.
    // lane l -> row += (l>>2), phys col-grp l&3, LOGICAL grp (l&3)^((l>>3)&3)
    // (= (l&3) ^ ((row>>1)&3), the inverse of the read-side swizzle).
    const int rl = lane >> 2;
    const int gS = (lane & 3) ^ ((lane >> 3) & 3);
    const u16* aS = A + (size_t)(M0 + wv * 32 + rl) * K + gS * 8;
    const u16* bS = W + (size_t)(N0 + wv * 32 + rl) * K + gS * 8;
    const size_t cstep = (size_t)16 * K;

    // fragment reads: row-local r = *16 + lr, k-grp qf: phys grp = qf^((lr>>1)&3)
    const int lr = lane & 15, qf = lane >> 4;
    const int fsw  = ((qf ^ ((lr >> 1) & 3)) << 3);
    const int arow = (wm * 128 + lr) * 32 + fsw;
    const int brow = (wn * 64 + lr) * 32 + fsw;

    const int nt = K >> 6;

    auto STAGE = [&](int mat, int t, int kh) {
        const u16* src = (mat ? bS : aS) + t * 64 + kh * 32;
        u16* dst = &LDS[t & 1][mat][kh][wv * 1024];
        glds16(src, dst);             // rows wv*32 .. +15
        glds16(src + cstep, dst + 512); // rows wv*32+16 .. +31
    };

    // prologue: tile0 (A+B, 8 calls) + tile1 B (4 calls); A(1) comes in-loop.
    STAGE(0, 0, 0); STAGE(0, 0, 1);
    STAGE(1, 0, 0); STAGE(1, 0, 1);
    if (nt > 1) {
        STAGE(1, 1, 0); STAGE(1, 1, 1);
        asm volatile("s_waitcnt vmcnt(4)" ::: "memory");
    } else {
        asm volatile("s_waitcnt vmcnt(0)" ::: "memory");
    }
    GBAR();

    for (int t = 0; t < nt; ++t) {
        const int b = t & 1;
        bf16x8 bF[4][2], a0[2], a1[2];

        // ---- phase 0: read all B + A m0,m1; stage A-kh0(t+1) ----
        PH_READ_A(0);
#pragma unroll
        for (int ni = 0; ni < 4; ++ni) {
            bF[ni][0] = *(const bf16x8*)&LDS[b][1][0][brow + ni * 512];
            bF[ni][1] = *(const bf16x8*)&LDS[b][1][1][brow + ni * 512];
        }
        if (t + 1 < nt) STAGE(0, t + 1, 0);
        GBAR(); LGKM0();
        PH_MFMA(0);
        GBAR();

        // ---- phase 1: A m2,m3; stage A-kh1(t+1) ----
        PH_READ_A(2);
        if (t + 1 < nt) STAGE(0, t + 1, 1);
        GBAR(); LGKM0();
        PH_MFMA(2);
        GBAR();

        // ---- phase 2: A m4,m5; stage B-kh0(t+2) (B(t) died after phase 0) --
        PH_READ_A(4);
        if (t + 2 < nt) STAGE(1, t + 2, 0);
        GBAR(); LGKM0();
        PH_MFMA(4);
        GBAR();

        // ---- phase 3: A m6,m7; stage B-kh1(t+2); tile-boundary vmcnt ----
        PH_READ_A(6);
        if (t + 2 < nt) STAGE(1, t + 2, 1);
        GBAR(); LGKM0();
        PH_MFMA(6);
        if (t + 2 < nt) asm volatile("s_waitcnt vmcnt(4)" ::: "memory");
        else            asm volatile("s_waitcnt vmcnt(0)" ::: "memory");
        GBAR();
    }

    // epilogue: C/D layout col = lane&15, row = (lane>>4)*4 + reg  [m89/m91]
    const int rb = M0 + wm * 128 + (qf << 2);
    const int cb = N0 + wn * 64 + lr;
    out_bf += (size_t)z * sC;
    out_f  += (size_t)z * sC;
#pragma unroll
    for (int mi = 0; mi < 8; ++mi) {
#pragma unroll
        for (int ni = 0; ni < 4; ++ni) {
            const int c = cb + ni * 16;
            const float bv = bias ? bias[c] : 0.f;
#pragma unroll
            for (int r = 0; r < 4; ++r) {
                const int rrw = rb + mi * 16 + r;
                float val = acc[mi][ni][r] + bv;
                if (mode == 0) {
                    out_bf[(size_t)rrw * N + c] = f2bf(val);
                } else if (mode == 1) {
                    out_bf[(size_t)rrw * N + c] = f2bf(val > 0.f ? val : 0.f);
                } else {
                    out_f[(size_t)rrw * N + c] =
                        val + bf2f(resid[(size_t)rrw * N + c]);
                }
            }
        }
    }
}

// ---------------------------------------------------------------------------
extern "C" void kernel_launch(void* const* d_in, const int* in_sizes, int n_in,
                              void* d_out, int out_size, void* d_ws, size_t ws_size,
                              hipStream_t stream) {
    const float* visual = (const float*)d_in[0];
    const float* text   = (const float*)d_in[1];
    const float* Wv_sv  = (const float*)d_in[2];
    const float* bv_sv  = (const float*)d_in[3];
    const float* Wo_sv  = (const float*)d_in[4];
    const float* bo_sv  = (const float*)d_in[5];
    const float* Wv_st  = (const float*)d_in[6];
    const float* bv_st  = (const float*)d_in[7];
    const float* Wo_st  = (const float*)d_in[8];
    const float* bo_st  = (const float*)d_in[9];
    const float* Wv_v2t = (const float*)d_in[10];
    const float* bv_v2t = (const float*)d_in[11];
    const float* Wo_v2t = (const float*)d_in[12];
    const float* bo_v2t = (const float*)d_in[13];
    const float* Wv_t2v = (const float*)d_in[14];
    const float* bv_t2v = (const float*)d_in[15];
    const float* Wo_t2v = (const float*)d_in[16];
    const float* bo_t2v = (const float*)d_in[17];
    const float* g_v1 = (const float*)d_in[18];
    const float* be_v1 = (const float*)d_in[19];
    const float* g_t1 = (const float*)d_in[20];
    const float* be_t1 = (const float*)d_in[21];
    const float* g_v2 = (const float*)d_in[22];
    const float* be_v2 = (const float*)d_in[23];
    const float* g_t2 = (const float*)d_in[24];
    const float* be_t2 = (const float*)d_in[25];
    const float* W1_v = (const float*)d_in[26];
    const float* b1_v = (const float*)d_in[27];
    const float* W2_v = (const float*)d_in[28];
    const float* b2_v = (const float*)d_in[29];
    const float* W1_t = (const float*)d_in[30];
    const float* b1_t = (const float*)d_in[31];
    const float* W2_t = (const float*)d_in[32];
    const float* b2_t = (const float*)d_in[33];

    const int Bsz = 16384, D = 1024, HID = 2048;
    const size_t SQ = (size_t)D * D;          // 1 Mi elems
    const size_t BD = (size_t)Bsz * D;        // 16 Mi elems

    // ws layout (u16 units of SQ):
    //  0.. 4  wWc[4]        (folded attn weights, bf16)
    //  4..12  wW1_v,wW2_v,wW1_t,wW2_t (2 SQ each)
    // 12..13  bias area: bc[4] fp32 (4*1024 floats) at the front
    // 13..29  P0 | 29..45 P1 | 45..61 P2 | 61..77 P3   (activations, 16 SQ ea)
    // temp (dead until LN-v2 writes P3): wWo[4] @ P3+0..4, wWvT[4] @ P3+4..8
    // total 77 SQ * 2B = 161.5 MB
    u16* wb = (u16*)d_ws;
    u16* wWc   = wb + 0 * SQ;
    u16* wW1_v = wb + 4 * SQ;
    u16* wW2_v = wb + 6 * SQ;
    u16* wW1_t = wb + 8 * SQ;
    u16* wW2_t = wb + 10 * SQ;
    float* bcAll = (float*)(wb + 12 * SQ);
    u16* P0 = wb + 13 * SQ;
    u16* P1 = wb + 29 * SQ;
    u16* P2 = wb + 45 * SQ;
    u16* P3 = wb + 61 * SQ;
    u16* Hbuf = P0;                       // 16384x2048 spans P0+P1
    u16* wWo  = P3;                       // temp, 4 SQ
    u16* wWvT = P3 + 4 * SQ;              // temp, 4 SQ

    float* out0 = (float*)d_out;
    float* out1 = out0 + BD;
    float* out2 = out0 + 2 * BD;

    auto cvt = [&](const float* src, u16* dst, size_t n) {
        cvtk<<<dim3((unsigned)(n / 1024)), dim3(256), 0, stream>>>(src, dst);
    };
    auto gemm = [&](const u16* Am, const u16* Wm, const float* bias, int M,
                    int N, int K, int mode, const u16* resid, void* out,
                    int zdim, size_t sA, size_t sW, size_t sC) {
        dim3 grid((unsigned)(N / 256), (unsigned)(M / 256), (unsigned)zdim);
        gemm256<<<grid, dim3(512), 0, stream>>>(Am, Wm, bias, M, N, K, mode,
                                                resid, (u16*)out, (float*)out,
                                                sA, sW, sC);
    };
    auto ln = [&](const float* x, const u16* a1, const u16* a2, float s,
                  const float* g, const float* be, u16* out) {
        ln_kernel<<<dim3(Bsz), dim3(256), 0, stream>>>(x, a1, a2, s, g, be, out);
    };

    // ---- weight prep (ws re-poisoned every call; must redo) ----
    cvt(Wo_sv, wWo + 0 * SQ, SQ);
    cvt(Wo_st, wWo + 1 * SQ, SQ);
    cvt(Wo_v2t, wWo + 2 * SQ, SQ);
    cvt(Wo_t2v, wWo + 3 * SQ, SQ);
    Ptr4 wvp = {{Wv_sv, Wv_st, Wv_v2t, Wv_t2v}};
    tcvtk<<<dim3(32, 32, 4), dim3(256), 0, stream>>>(wvp, wWvT);
    cvt(W1_v, wW1_v, 2 * SQ); cvt(W2_v, wW2_v, 2 * SQ);
    cvt(W1_t, wW1_t, 2 * SQ); cvt(W2_t, wW2_t, 2 * SQ);

    // Wc_z = Wo_z @ Wv_z  (= gemm(Wo_z, WvT_z)), batched z=4
    gemm(wWo, wWvT, nullptr, D, D, D, 0, nullptr, wWc, 4, SQ, SQ, SQ);
    // bc_z = Wo_z @ bv_z + bo_z (fp32)
    BiasArgs ba = {{Wo_sv, Wo_st, Wo_v2t, Wo_t2v},
                   {bv_sv, bv_st, bv_v2t, bv_t2v},
                   {bo_sv, bo_st, bo_v2t, bo_t2v}};
    biask<<<dim3(256, 4), dim3(256), 0, stream>>>(ba, bcAll);
    const float* bc_sv  = bcAll;
    const float* bc_st  = bcAll + 1024;
    const float* bc_v2t = bcAll + 2048;
    const float* bc_t2v = bcAll + 3072;

    // ---- forward ----
    // v_self = LN(visual + visual@Wc_sv^T + bc_sv)
    cvt(visual, P0, BD);
    gemm(P0, wWc + 0 * SQ, bc_sv, Bsz, D, D, 0, nullptr, P1, 1, 0, 0, 0);
    ln(visual, P1, nullptr, 1.f, g_v1, be_v1, P1);          // P1 = VS
    // t_self
    cvt(text, P0, BD);
    gemm(P0, wWc + 1 * SQ, bc_st, Bsz, D, D, 0, nullptr, P2, 1, 0, 0, 0);
    ln(text, P2, nullptr, 1.f, g_t1, be_t1, P2);            // P2 = TS

    // v_cross = TS@Wc_v2t^T + bc; v_fused = LN(visual + 0.5*(VS+VC))
    gemm(P2, wWc + 2 * SQ, bc_v2t, Bsz, D, D, 0, nullptr, P0, 1, 0, 0, 0); // P0=VC
    ln(visual, P1, P0, 0.5f, g_v2, be_v2, P3);              // P3 = VF
    // t_cross = VS@Wc_t2v^T + bc; t_fused = LN(text + 0.5*(TS+TC))
    gemm(P1, wWc + 3 * SQ, bc_t2v, Bsz, D, D, 0, nullptr, P0, 1, 0, 0, 0); // P0=TC
    ln(text, P2, P0, 0.5f, g_t2, be_t2, P2);                // P2 = TF

    // v_out = VF + ffn_v(VF)
    gemm(P3, wW1_v, b1_v, Bsz, HID, D, 1, nullptr, Hbuf, 1, 0, 0, 0);
    gemm(Hbuf, wW2_v, b2_v, Bsz, D, HID, 2, P3, out0, 1, 0, 0, 0);
    // t_out = TF + ffn_t(TF)
    gemm(P2, wW1_t, b1_t, Bsz, HID, D, 1, nullptr, Hbuf, 1, 0, 0, 0);
    gemm(Hbuf, wW2_t, b2_t, Bsz, D, HID, 2, P2, out1, 1, 0, 0, 0);

    // new_context
    ctxk<<<dim3((unsigned)(BD / 1024)), dim3(256), 0, stream>>>(out0, out1, out2);
}

// Round 2
// 1114.838 us; speedup vs baseline: 1.2309x; 1.0062x over previous
//
#include <hip/hip_runtime.h>
#include <stdint.h>

// EfficientFusionLayer on MI355X (gfx950).  B=16384, DIM=1024, HID=2048.
// fp32 in/out; internals bf16 MFMA (16x16x32).
// seq-len-1 MHA folded: attn(x) = x@(Wo@Wv)^T + (Wo@bv + bo)  -- one GEMM.
// GEMM: 256x256 tile, BK=64, 8 waves, 4 balanced phases/K-tile (8/4/8/4
// ds_read_b128), counted vmcnt(4) at tile boundary, setprio around MFMA.
// All v/t GEMM pairs z-batched (bias/resid z-strides); elementwise batched.

typedef unsigned short u16;
typedef __bf16 bf16x8 __attribute__((ext_vector_type(8)));
typedef float f32x4 __attribute__((ext_vector_type(4)));

__device__ __forceinline__ u16 f2bf(float f) {
    uint32_t x = __float_as_uint(f);
    uint32_t r = (x + 0x7fffu + ((x >> 16) & 1u)) >> 16;   // round-nearest-even
    return (u16)r;
}
__device__ __forceinline__ float bf2f(u16 u) {
    return __uint_as_float(((uint32_t)u) << 16);
}

// async global->LDS, 16B per lane; deposit = wave-uniform base + lane*16
__device__ __forceinline__ void glds16(const u16* g, u16* l) {
    __builtin_amdgcn_global_load_lds(
        (__attribute__((address_space(1))) void*)g,
        (__attribute__((address_space(3))) void*)l, 16, 0, 0);
}

// ---------------------------------------------------------------------------
// batched fp32 -> bf16 convert: z = blockIdx.y, dst = base + z*zstride
struct Ptr4 { const float* p[4]; };
__global__ __launch_bounds__(256) void cvt4k(Ptr4 src, u16* __restrict__ dst,
                                             size_t zstride) {
    const int z = blockIdx.y;
    size_t i = ((size_t)blockIdx.x * 256 + threadIdx.x) * 4;
    float4 v = *(const float4*)&src.p[z][i];
    ushort4 o;
    o.x = f2bf(v.x); o.y = f2bf(v.y); o.z = f2bf(v.z); o.w = f2bf(v.w);
    *(ushort4*)&dst[z * zstride + i] = o;
}

// transposing fp32 -> bf16 convert for the 4 Wv matrices (1024x1024 each)
__global__ __launch_bounds__(256) void tcvtk(Ptr4 src, u16* __restrict__ dst) {
    __shared__ float t[32][33];
    const int z = blockIdx.z;
    const float* s = src.p[z];
    const int bx = blockIdx.x * 32, by = blockIdx.y * 32;
    const int tx = threadIdx.x & 31, ty = threadIdx.x >> 5;   // 32 x 8
#pragma unroll
    for (int i = 0; i < 32; i += 8)
        t[ty + i][tx] = s[(size_t)(by + ty + i) * 1024 + bx + tx];
    __syncthreads();
    u16* d = dst + (size_t)z * (1024 * 1024);
#pragma unroll
    for (int i = 0; i < 32; i += 8)
        d[(size_t)(bx + ty + i) * 1024 + by + tx] = f2bf(t[tx][ty + i]);
}

// fused bias: bc_z[r] = dot(Wo_z[r,:], bv_z) + bo_z[r]  (fp32, exact inputs)
struct BiasArgs { const float* Wo[4]; const float* bv[4]; const float* bo[4]; };
__global__ __launch_bounds__(256) void biask(BiasArgs a, float* __restrict__ out) {
    const int z = blockIdx.y;
    const int row = blockIdx.x * 4 + (threadIdx.x >> 6);
    const int lane = threadIdx.x & 63;
    const float* w = a.Wo[z] + (size_t)row * 1024 + lane * 16;
    const float* v = a.bv[z] + lane * 16;
    float s = 0.f;
#pragma unroll
    for (int i = 0; i < 16; i += 4) {
        float4 w4 = *(const float4*)&w[i];
        float4 v4 = *(const float4*)&v[i];
        s += w4.x * v4.x + w4.y * v4.y + w4.z * v4.z + w4.w * v4.w;
    }
#pragma unroll
    for (int o = 1; o < 64; o <<= 1) s += __shfl_xor(s, o);
    if (lane == 0) out[(size_t)z * 1024 + row] = s + a.bo[z][row];
}

// concat FFN biases: b1_v(2048) | b1_t(2048) | b2_v(1024) | b2_t(1024)
__global__ __launch_bounds__(256) void copyb(const float* a, const float* b,
                                             const float* c, const float* d,
                                             float* __restrict__ o) {
    int i = blockIdx.x * 1024 + threadIdx.x * 4;   // grid 6
    float4 v;
    if (i < 2048)      v = *(const float4*)&a[i];
    else if (i < 4096) v = *(const float4*)&b[i - 2048];
    else if (i < 5120) v = *(const float4*)&c[i - 4096];
    else               v = *(const float4*)&d[i - 5120];
    *(float4*)&o[i] = v;
}

// new_context = 0.5*(v_out + t_out)
__global__ __launch_bounds__(256) void ctxk(const float* __restrict__ a,
                                            const float* __restrict__ b,
                                            float* __restrict__ o) {
    size_t i = ((size_t)blockIdx.x * 256 + threadIdx.x) * 4;
    float4 va = *(const float4*)&a[i];
    float4 vb = *(const float4*)&b[i];
    float4 vo;
    vo.x = 0.5f * (va.x + vb.x); vo.y = 0.5f * (va.y + vb.y);
    vo.z = 0.5f * (va.z + vb.z); vo.w = 0.5f * (va.w + vb.w);
    *(float4*)&o[i] = vo;
}

// ---------------------------------------------------------------------------
// batched LayerNorm over D=1024 (blockIdx.y selects v/t parameter set):
// out_bf16 = LN(x_f32 + s*(a1_bf16 [+ a2_bf16])) * g + be
struct LnArgs {
    const float* x[2]; const u16* a1[2]; const u16* a2[2];
    const float* g[2]; const float* be[2]; u16* out[2]; float s;
};
__global__ __launch_bounds__(256) void ln2_kernel(LnArgs A) {
    const int y = blockIdx.y;
    const int tid = threadIdx.x;
    const size_t base = (size_t)blockIdx.x * 1024;
    const int i0 = tid * 4;

    float4 xv = *(const float4*)&A.x[y][base + i0];
    ushort4 u1 = *(const ushort4*)&A.a1[y][base + i0];
    float add[4] = {bf2f(u1.x), bf2f(u1.y), bf2f(u1.z), bf2f(u1.w)};
    if (A.a2[y]) {
        ushort4 u2 = *(const ushort4*)&A.a2[y][base + i0];
        add[0] += bf2f(u2.x); add[1] += bf2f(u2.y);
        add[2] += bf2f(u2.z); add[3] += bf2f(u2.w);
    }
    float v[4] = {xv.x, xv.y, xv.z, xv.w};
    float sum = 0.f, ss = 0.f;
#pragma unroll
    for (int j = 0; j < 4; ++j) {
        v[j] += A.s * add[j];
        sum += v[j];
        ss += v[j] * v[j];
    }
#pragma unroll
    for (int o = 1; o < 64; o <<= 1) {
        sum += __shfl_xor(sum, o);
        ss  += __shfl_xor(ss, o);
    }
    __shared__ float s1[4], s2[4];
    if ((tid & 63) == 0) { s1[tid >> 6] = sum; s2[tid >> 6] = ss; }
    __syncthreads();
    sum = s1[0] + s1[1] + s1[2] + s1[3];
    ss  = s2[0] + s2[1] + s2[2] + s2[3];
    const float mean = sum * (1.f / 1024.f);
    const float var  = ss * (1.f / 1024.f) - mean * mean;
    const float inv  = rsqrtf(var + 1e-5f);

    float4 gv = *(const float4*)&A.g[y][i0];
    float4 bv = *(const float4*)&A.be[y][i0];
    ushort4 o4;
    o4.x = f2bf((v[0] - mean) * inv * gv.x + bv.x);
    o4.y = f2bf((v[1] - mean) * inv * gv.y + bv.y);
    o4.z = f2bf((v[2] - mean) * inv * gv.z + bv.z);
    o4.w = f2bf((v[3] - mean) * inv * gv.w + bv.w);
    *(ushort4*)&A.out[y][base + i0] = o4;
}

// ---------------------------------------------------------------------------
// NT GEMM: C[M,N] = A[M,K] @ W[N,K]^T + bias, bf16 in, fp32 acc.
// 256x256 tile, BK=64, 512 thr (8 waves, 2Mx4N), per-wave C = 128x64.
// 4 phases/K-tile split by k-half (balanced ds_read: 8/4/8/4 per phase):
//   ph0: A m0-3 kh0 + B kh0; stage A(t+1)kh0; bar; lgkm0; 16 MFMA; bar
//   ph1: A m4-7 kh0;         stage A(t+1)kh1; ...
//   ph2: A m0-3 kh1 + B kh1; stage B(t+2)kh0; ...
//   ph3: A m4-7 kh1;         stage B(t+2)kh1; MFMA; vmcnt(4); bar
// vmcnt(4) leaves the 4 B(t+2) loads in flight across the boundary (T4);
// youngest drained load (A(t+1)kh1) is 2 phases (~1600cy) old > HBM latency.
// LDS [buf][A/B][khalf][256 rows x 32 cols], col-group XOR swizzle
// grp_phys = grp ^ ((row>>1)&3) (verified 0 bank conflicts in R1 family).
// Staging deposit is linear; inverse swizzle applied to per-lane GLOBAL src.
// mode 0: bf16 out = acc+bias   1: bf16 out = relu(acc+bias)
// mode 2: fp32 out = acc+bias+bf2f(resid)
// z-batching: A/W/C strides sA/sW/sC, bias stride sB, resid stride sR (elems).
#define GBAR()  asm volatile("s_barrier" ::: "memory")
#define LGKM0() asm volatile("s_waitcnt lgkmcnt(0)" ::: "memory")

__global__ __launch_bounds__(512, 2) void gemm256(
    const u16* __restrict__ A, const u16* __restrict__ W,
    const float* __restrict__ bias,
    int M, int N, int K, int mode,
    const u16* __restrict__ resid,
    u16* __restrict__ out_bf, float* __restrict__ out_f,
    size_t sA, size_t sW, size_t sC, size_t sB, size_t sR) {
    __shared__ u16 LDS[2][2][2][8192];   // [buf][A/B][khalf][256*32] = 128 KiB

    const int tid  = threadIdx.x;
    const int lane = tid & 63;
    const int wv   = tid >> 6;               // 0..7
    const int wm   = wv >> 2, wn = wv & 3;   // 2 x 4 wave grid

    // T1: bijective XCD-chunked swizzle (m204)
    const int gx   = gridDim.x;
    const int nwg  = gx * gridDim.y;
    const int orig = blockIdx.y * gx + blockIdx.x;
    const int qq = nwg >> 3, rr = nwg & 7;
    const int xcd = orig & 7, loc = orig >> 3;
    const int wgid =
        (xcd < rr ? xcd * (qq + 1) : rr * (qq + 1) + (xcd - rr) * qq) + loc;
    const int M0 = (wgid / gx) * 256, N0 = (wgid % gx) * 256;

    const int z = blockIdx.z;
    A += (size_t)z * sA;
    W += (size_t)z * sW;

    const f32x4 fz = {0.f, 0.f, 0.f, 0.f};
    f32x4 acc[8][4];
#pragma unroll
    for (int i = 0; i < 8; ++i)
#pragma unroll
        for (int j = 0; j < 4; ++j) acc[i][j] = fz;

    // staging: wave wv covers tile rows [wv*32, wv*32+32); call c adds 16 rows.
    // lane l -> row += (l>>2), phys col-grp l&3, LOGICAL grp (l&3)^((l>>3)&3)
    const int rl = lane >> 2;
    const int gS = (lane & 3) ^ ((lane >> 3) & 3);
    const u16* aS = A + (size_t)(M0 + wv * 32 + rl) * K + gS * 8;
    const u16* bS = W + (size_t)(N0 + wv * 32 + rl) * K + gS * 8;
    const size_t cstep = (size_t)16 * K;

    // fragment reads: row-local r = *16 + lr, k-grp qf: phys grp = qf^((lr>>1)&3)
    const int lr = lane & 15, qf = lane >> 4;
    const int fsw  = ((qf ^ ((lr >> 1) & 3)) << 3);
    const int arow = (wm * 128 + lr) * 32 + fsw;
    const int brow = (wn * 64 + lr) * 32 + fsw;

    const int nt = K >> 6;

    auto STAGE = [&](int mat, int t, int kh) {
        const u16* src = (mat ? bS : aS) + t * 64 + kh * 32;
        u16* dst = &LDS[t & 1][mat][kh][wv * 1024];
        glds16(src, dst);               // rows wv*32 .. +15
        glds16(src + cstep, dst + 512); // rows wv*32+16 .. +31
    };

    // prologue: tile0 (A+B, 8 loads) + tile1 B (4 loads); A(1) staged in-loop.
    STAGE(0, 0, 0); STAGE(0, 0, 1);
    STAGE(1, 0, 0); STAGE(1, 0, 1);
    if (nt > 1) {
        STAGE(1, 1, 0); STAGE(1, 1, 1);
        asm volatile("s_waitcnt vmcnt(4)" ::: "memory");
    } else {
        asm volatile("s_waitcnt vmcnt(0)" ::: "memory");
    }
    GBAR();

    for (int t = 0; t < nt; ++t) {
        const int b = t & 1;
        bf16x8 aF[4], bK[4];

        // ---- phase 0: A m0-3 kh0 + B kh0 (8 reads); stage A(t+1)kh0 ----
#pragma unroll
        for (int mi = 0; mi < 4; ++mi)
            aF[mi] = *(const bf16x8*)&LDS[b][0][0][arow + mi * 512];
#pragma unroll
        for (int ni = 0; ni < 4; ++ni)
            bK[ni] = *(const bf16x8*)&LDS[b][1][0][brow + ni * 512];
        if (t + 1 < nt) STAGE(0, t + 1, 0);
        GBAR(); LGKM0();
        __builtin_amdgcn_s_setprio(1);
#pragma unroll
        for (int mi = 0; mi < 4; ++mi)
#pragma unroll
            for (int ni = 0; ni < 4; ++ni)
                acc[mi][ni] = __builtin_amdgcn_mfma_f32_16x16x32_bf16(
                    aF[mi], bK[ni], acc[mi][ni], 0, 0, 0);
        __builtin_amdgcn_s_setprio(0);
        GBAR();

        // ---- phase 1: A m4-7 kh0 (4 reads); stage A(t+1)kh1 ----
#pragma unroll
        for (int mi = 0; mi < 4; ++mi)
            aF[mi] = *(const bf16x8*)&LDS[b][0][0][arow + (mi + 4) * 512];
        if (t + 1 < nt) STAGE(0, t + 1, 1);
        GBAR(); LGKM0();
        __builtin_amdgcn_s_setprio(1);
#pragma unroll
        for (int mi = 0; mi < 4; ++mi)
#pragma unroll
            for (int ni = 0; ni < 4; ++ni)
                acc[mi + 4][ni] = __builtin_amdgcn_mfma_f32_16x16x32_bf16(
                    aF[mi], bK[ni], acc[mi + 4][ni], 0, 0, 0);
        __builtin_amdgcn_s_setprio(0);
        GBAR();

        // ---- phase 2: A m0-3 kh1 + B kh1 (8 reads); stage B(t+2)kh0 ----
#pragma unroll
        for (int mi = 0; mi < 4; ++mi)
            aF[mi] = *(const bf16x8*)&LDS[b][0][1][arow + mi * 512];
#pragma unroll
        for (int ni = 0; ni < 4; ++ni)
            bK[ni] = *(const bf16x8*)&LDS[b][1][1][brow + ni * 512];
        if (t + 2 < nt) STAGE(1, t + 2, 0);
        GBAR(); LGKM0();
        __builtin_amdgcn_s_setprio(1);
#pragma unroll
        for (int mi = 0; mi < 4; ++mi)
#pragma unroll
            for (int ni = 0; ni < 4; ++ni)
                acc[mi][ni] = __builtin_amdgcn_mfma_f32_16x16x32_bf16(
                    aF[mi], bK[ni], acc[mi][ni], 0, 0, 0);
        __builtin_amdgcn_s_setprio(0);
        GBAR();

        // ---- phase 3: A m4-7 kh1 (4 reads); stage B(t+2)kh1; boundary ----
#pragma unroll
        for (int mi = 0; mi < 4; ++mi)
            aF[mi] = *(const bf16x8*)&LDS[b][0][1][arow + (mi + 4) * 512];
        if (t + 2 < nt) STAGE(1, t + 2, 1);
        GBAR(); LGKM0();
        __builtin_amdgcn_s_setprio(1);
#pragma unroll
        for (int mi = 0; mi < 4; ++mi)
#pragma unroll
            for (int ni = 0; ni < 4; ++ni)
                acc[mi + 4][ni] = __builtin_amdgcn_mfma_f32_16x16x32_bf16(
                    aF[mi], bK[ni], acc[mi + 4][ni], 0, 0, 0);
        __builtin_amdgcn_s_setprio(0);
        if (t + 2 < nt) asm volatile("s_waitcnt vmcnt(4)" ::: "memory");
        else            asm volatile("s_waitcnt vmcnt(0)" ::: "memory");
        GBAR();
    }

    // epilogue: C/D layout col = lane&15, row = (lane>>4)*4 + reg  [m89/m91]
    const int rb = M0 + wm * 128 + (qf << 2);
    const int cb = N0 + wn * 64 + lr;
    out_bf += (size_t)z * sC;
    out_f  += (size_t)z * sC;
    const float* bz = bias ? bias + (size_t)z * sB : nullptr;
    const u16* rz = resid ? resid + (size_t)z * sR : nullptr;
#pragma unroll
    for (int mi = 0; mi < 8; ++mi) {
#pragma unroll
        for (int ni = 0; ni < 4; ++ni) {
            const int c = cb + ni * 16;
            const float bv = bz ? bz[c] : 0.f;
#pragma unroll
            for (int r = 0; r < 4; ++r) {
                const int rrw = rb + mi * 16 + r;
                float val = acc[mi][ni][r] + bv;
                if (mode == 0) {
                    out_bf[(size_t)rrw * N + c] = f2bf(val);
                } else if (mode == 1) {
                    out_bf[(size_t)rrw * N + c] = f2bf(val > 0.f ? val : 0.f);
                } else {
                    out_f[(size_t)rrw * N + c] =
                        val + bf2f(rz[(size_t)rrw * N + c]);
                }
            }
        }
    }
}

// ---------------------------------------------------------------------------
extern "C" void kernel_launch(void* const* d_in, const int* in_sizes, int n_in,
                              void* d_out, int out_size, void* d_ws, size_t ws_size,
                              hipStream_t stream) {
    const float* visual = (const float*)d_in[0];
    const float* text   = (const float*)d_in[1];
    const float* Wv_sv  = (const float*)d_in[2];
    const float* bv_sv  = (const float*)d_in[3];
    const float* Wo_sv  = (const float*)d_in[4];
    const float* bo_sv  = (const float*)d_in[5];
    const float* Wv_st  = (const float*)d_in[6];
    const float* bv_st  = (const float*)d_in[7];
    const float* Wo_st  = (const float*)d_in[8];
    const float* bo_st  = (const float*)d_in[9];
    const float* Wv_v2t = (const float*)d_in[10];
    const float* bv_v2t = (const float*)d_in[11];
    const float* Wo_v2t = (const float*)d_in[12];
    const float* bo_v2t = (const float*)d_in[13];
    const float* Wv_t2v = (const float*)d_in[14];
    const float* bv_t2v = (const float*)d_in[15];
    const float* Wo_t2v = (const float*)d_in[16];
    const float* bo_t2v = (const float*)d_in[17];
    const float* g_v1 = (const float*)d_in[18];
    const float* be_v1 = (const float*)d_in[19];
    const float* g_t1 = (const float*)d_in[20];
    const float* be_t1 = (const float*)d_in[21];
    const float* g_v2 = (const float*)d_in[22];
    const float* be_v2 = (const float*)d_in[23];
    const float* g_t2 = (const float*)d_in[24];
    const float* be_t2 = (const float*)d_in[25];
    const float* W1_v = (const float*)d_in[26];
    const float* b1_v = (const float*)d_in[27];
    const float* W2_v = (const float*)d_in[28];
    const float* b2_v = (const float*)d_in[29];
    const float* W1_t = (const float*)d_in[30];
    const float* b1_t = (const float*)d_in[31];
    const float* W2_t = (const float*)d_in[32];
    const float* b2_t = (const float*)d_in[33];

    const int Bsz = 16384, D = 1024, HID = 2048;
    const size_t SQ = (size_t)D * D;          // 1 Mi elems
    const size_t BD = (size_t)Bsz * D;        // 16 Mi elems (= 16 SQ)

    // ws layout (u16 units of SQ); ws is 768 MiB (the poison fill showed
    // WRITE_SIZE = 786432 KB), so 216 SQ = 432 MB fits.
    //   0..  4  wWc[4]   order: sv, st, t2v, v2t  (cross z-trick)
    //   4..  8  wW1_v, wW1_t   (2 SQ each)
    //   8.. 12  wW2_v, wW2_t
    //  12.. 13  fp32 bias area: bc[4x1024] | bF1[2x2048] | bF2[2x1024]
    //  16.. 48  XA: cvt(visual) | cvt(text)
    //  48.. 80  XS: VS | TS           (GEMM out, then LN'd in place)
    //  80..112  XC: TC | VC
    // 112..144  XF: VF | TF
    // 144..208  H : H_v | H_t         (16384x2048 each)
    // 208..216  temp: wWo[4] | wWvT[4]
    u16* wb = (u16*)d_ws;
    u16* wWc  = wb + 0 * SQ;
    u16* wW1  = wb + 4 * SQ;
    u16* wW2  = wb + 8 * SQ;
    float* bcAll = (float*)(wb + 12 * SQ);
    float* bF1   = bcAll + 4096;
    float* bF2   = bcAll + 8192;
    u16* XA = wb + 16 * SQ;
    u16* XS = wb + 48 * SQ;
    u16* XC = wb + 80 * SQ;
    u16* XF = wb + 112 * SQ;
    u16* H  = wb + 144 * SQ;
    u16* wWo  = wb + 208 * SQ;
    u16* wWvT = wb + 212 * SQ;

    float* out0 = (float*)d_out;
    float* out1 = out0 + BD;
    float* out2 = out0 + 2 * BD;

    auto gemm = [&](const u16* Am, const u16* Wm, const float* bias, int M,
                    int N, int K, int mode, const u16* resid, void* out,
                    int zdim, size_t sA, size_t sW, size_t sC, size_t sB,
                    size_t sR) {
        dim3 grid((unsigned)(N / 256), (unsigned)(M / 256), (unsigned)zdim);
        gemm256<<<grid, dim3(512), 0, stream>>>(Am, Wm, bias, M, N, K, mode,
                                                resid, (u16*)out, (float*)out,
                                                sA, sW, sC, sB, sR);
    };

    // ---- weight prep (ws re-poisoned every call; must redo) ----
    Ptr4 wop = {{Wo_sv, Wo_st, Wo_t2v, Wo_v2t}};
    cvt4k<<<dim3(1024, 4), dim3(256), 0, stream>>>(wop, wWo, SQ);
    Ptr4 wvp = {{Wv_sv, Wv_st, Wv_t2v, Wv_v2t}};
    tcvtk<<<dim3(32, 32, 4), dim3(256), 0, stream>>>(wvp, wWvT);
    Ptr4 w12 = {{W1_v, W1_t, W2_v, W2_t}};
    cvt4k<<<dim3(2048, 4), dim3(256), 0, stream>>>(w12, wW1, 2 * SQ);
    copyb<<<dim3(6), dim3(256), 0, stream>>>(b1_v, b1_t, b2_v, b2_t, bF1);

    // Wc_z = Wo_z @ Wv_z  (= gemm(Wo_z, WvT_z)), batched z=4
    gemm(wWo, wWvT, nullptr, D, D, D, 0, nullptr, wWc, 4, SQ, SQ, SQ, 0, 0);
    // bc_z = Wo_z @ bv_z + bo_z (fp32), order matches wWc
    BiasArgs ba = {{Wo_sv, Wo_st, Wo_t2v, Wo_v2t},
                   {bv_sv, bv_st, bv_t2v, bv_v2t},
                   {bo_sv, bo_st, bo_t2v, bo_v2t}};
    biask<<<dim3(256, 4), dim3(256), 0, stream>>>(ba, bcAll);

    // ---- forward ----
    // inputs -> bf16 (batched)
    Ptr4 inp = {{visual, text, nullptr, nullptr}};
    cvt4k<<<dim3(16384, 2), dim3(256), 0, stream>>>(inp, XA, BD);

    // self: z=0 visual@Wc_sv, z=1 text@Wc_st -> XS
    gemm(XA, wWc, bcAll, Bsz, D, D, 0, nullptr, XS, 2, BD, SQ, BD, 1024, 0);
    // LN in place: VS = LN(visual + S_v), TS = LN(text + S_t)
    {
        LnArgs la = {{visual, text}, {XS, XS + BD}, {nullptr, nullptr},
                     {g_v1, g_t1}, {be_v1, be_t1}, {XS, XS + BD}, 1.f};
        ln2_kernel<<<dim3(16384, 2), dim3(256), 0, stream>>>(la);
    }

    // cross: z=0 VS@Wc_t2v -> TC, z=1 TS@Wc_v2t -> VC
    gemm(XS, wWc + 2 * SQ, bcAll + 2048, Bsz, D, D, 0, nullptr, XC, 2,
         BD, SQ, BD, 1024, 0);
    // fused LN: VF = LN(visual + .5*(VS+VC)), TF = LN(text + .5*(TS+TC))
    {
        LnArgs la = {{visual, text}, {XS, XS + BD}, {XC + BD, XC},
                     {g_v2, g_t2}, {be_v2, be_t2}, {XF, XF + BD}, 0.5f};
        ln2_kernel<<<dim3(16384, 2), dim3(256), 0, stream>>>(la);
    }

    // FFN1 (relu): z=0 VF@W1_v -> H_v, z=1 TF@W1_t -> H_t
    gemm(XF, wW1, bF1, Bsz, HID, D, 1, nullptr, H, 2, BD, 2 * SQ, 2 * BD,
         2048, 0);
    // FFN2 (+resid): z=0 H_v@W2_v + VF -> out0, z=1 H_t@W2_t + TF -> out1
    gemm(H, wW2, bF2, Bsz, D, HID, 2, XF, out0, 2, 2 * BD, 2 * SQ, BD,
         1024, BD);

    // new_context
    ctxk<<<dim3((unsigned)(BD / 1024)), dim3(256), 0, stream>>>(out0, out1, out2);
}